// Round 4
// baseline (161.278 us; speedup 1.0000x reference)
//
#include <hip/hip_runtime.h>
#include <hip/hip_bf16.h>
#include <stdint.h>

#define VOCAB 100000
#define SEQ   8192
#define BATCH 8
#define DIM   128

#define WLT_BLOCKS 1563          // ceil(100000/64)
#define WCONV_BLOCKS 320         // 5*128*128 / 256

typedef short bf16x8 __attribute__((ext_vector_type(8)));
typedef float f32x4  __attribute__((ext_vector_type(4)));

__device__ __forceinline__ ushort f2bf(float f) {
  union { float f; uint32_t u; } v; v.f = f;
  uint32_t u = v.u;
  return (ushort)((u + 0x7FFF + ((u >> 16) & 1)) >> 16);  // RNE; inputs never NaN
}

// ---------------------------------------------------------------------------
// Prep kernel (merged): blocks [0, WLT_BLOCKS) build wlt via LDS tile
// transpose; blocks [WLT_BLOCKS, +320) repack W_conv (d,i,k)->wcb[k][d][i].
// ---------------------------------------------------------------------------
__global__ __launch_bounds__(256) void prep(
    const float* __restrict__ wlin, const float* __restrict__ blin,
    const float* __restrict__ wconv, ushort* __restrict__ wlt,
    ushort* __restrict__ wcb) {
  __shared__ float tile[128 * 65];
  const int tid = threadIdx.x;

  if (blockIdx.x >= WLT_BLOCKS) {
    int e = (blockIdx.x - WLT_BLOCKS) * 256 + tid;   // < 81920
    int k = e / (DIM * DIM);
    int rem = e % (DIM * DIM);
    int d = rem / DIM, i = rem % DIM;
    wcb[e] = f2bf(wconv[(d * DIM + i) * 5 + k]);
    return;
  }

  const int t0 = blockIdx.x * 64;

  // Phase A: float4 coalesced reads of W_lin rows into fp32 LDS tile.
  const int c4 = (tid & 15) * 4;
  const int rbase = tid >> 4;
  const bool cvalid = (t0 + c4) < VOCAB;   // VOCAB%4==0 -> whole float4 ok
#pragma unroll
  for (int p = 0; p < 8; ++p) {
    int r = p * 16 + rbase;
    float4 v = make_float4(0.f, 0.f, 0.f, 0.f);
    if (cvalid) v = *(const float4*)(wlin + (size_t)r * VOCAB + t0 + c4);
    float* dst = &tile[r * 65 + c4];
    dst[0] = v.x; dst[1] = v.y; dst[2] = v.z; dst[3] = v.w;
  }
  __syncthreads();

  // Phase B: transposed reads (+bias), bf16 pack, contiguous 1KB/wave stores.
  const int chunk = tid & 15;
  float bias8[8];
#pragma unroll
  for (int j = 0; j < 8; ++j) bias8[j] = blin[chunk * 8 + j];

#pragma unroll
  for (int p = 0; p < 4; ++p) {
    int tl = (tid >> 4) + p * 16;
    int t  = t0 + tl;
    if (t >= VOCAB) continue;
    ushort u[8];
#pragma unroll
    for (int j = 0; j < 8; ++j)
      u[j] = f2bf(tile[(chunk * 8 + j) * 65 + tl] + bias8[j]);
    *(uint4*)(wlt + (size_t)t * DIM + chunk * 8) = *(const uint4*)u;
  }
}

// ---------------------------------------------------------------------------
// Main (LDS-free): wave = 32 rows x 128 channels. A-fragments gathered
// DIRECTLY from wlt: lane(lr,lq) of frag (mt,k,kk) reads 16B at
// wlt[tok(n0+mt*16+lr+k-2)] + kk*64B + lq*16B -- a wlt row IS the A-frag
// layout A[m=lane&15][k=(lane>>4)*8+j]. No LDS, no barriers; latency hidden
// by ILP over 40 independent gathers + 160 B-loads per wave, 320 MFMAs.
// ---------------------------------------------------------------------------
template <bool EDGE>
__device__ __forceinline__ void conv_wave(
    const int* __restrict__ Xb, const ushort* __restrict__ wlt,
    const ushort* __restrict__ wcb, const float* __restrict__ bconv,
    const float* __restrict__ pos, float* __restrict__ outb,
    int n0, int lr, int lq) {
  // tokens for rows n0 + mt*16 + lr + (k-2)
  int  tok[2][5];
  bool vld[2][5];
#pragma unroll
  for (int mt = 0; mt < 2; ++mt)
#pragma unroll
    for (int k = 0; k < 5; ++k) {
      int n = n0 + mt * 16 + lr + k - 2;
      bool v = EDGE ? (n >= 0 && n < SEQ) : true;
      vld[mt][k] = v;
      tok[mt][k] = v ? Xb[n] : 0;
    }

  f32x4 acc[2][8];
#pragma unroll
  for (int mt = 0; mt < 2; ++mt)
#pragma unroll
    for (int nt = 0; nt < 8; ++nt) acc[mt][nt] = (f32x4)0.f;

  const int colA = lq * 8;            // ushort offset within a 128-elem row
#pragma unroll
  for (int k = 0; k < 5; ++k) {
    bf16x8 A[2][4];
#pragma unroll
    for (int mt = 0; mt < 2; ++mt)
#pragma unroll
      for (int kk = 0; kk < 4; ++kk) {
        bf16x8 v = *(const bf16x8*)(wlt + ((size_t)tok[mt][k] << 7) + kk * 32 + colA);
        A[mt][kk] = (EDGE && !vld[mt][k]) ? (bf16x8)(short)0 : v;
      }
#pragma unroll
    for (int kk = 0; kk < 4; ++kk) {
      bf16x8 B[8];
#pragma unroll
      for (int nt = 0; nt < 8; ++nt)
        B[nt] = *(const bf16x8*)(wcb +
            ((size_t)(k * DIM + nt * 16 + lr) * DIM + kk * 32 + colA));
#pragma unroll
      for (int mt = 0; mt < 2; ++mt)
#pragma unroll
        for (int nt = 0; nt < 8; ++nt)
          acc[mt][nt] = __builtin_amdgcn_mfma_f32_16x16x32_bf16(
              A[mt][kk], B[nt], acc[mt][nt], 0, 0, 0);
    }
  }

  // epilogue: + b_conv[d] + pos[n][d]; C layout: col(d)=lr, row(m)=lq*4+rr
  float bc[8];
#pragma unroll
  for (int nt = 0; nt < 8; ++nt) bc[nt] = bconv[nt * 16 + lr];
#pragma unroll
  for (int mt = 0; mt < 2; ++mt) {
#pragma unroll
    for (int rr = 0; rr < 4; ++rr) {
      int gn = n0 + mt * 16 + lq * 4 + rr;
      const float* posrow = pos + (size_t)gn * DIM;
      float* orow = outb + (size_t)gn * DIM;
#pragma unroll
      for (int nt = 0; nt < 8; ++nt) {
        int d = nt * 16 + lr;
        orow[d] = acc[mt][nt][rr] + bc[nt] + posrow[d];
      }
    }
  }
}

__global__ __launch_bounds__(256, 2) void conv_main(
    const int* __restrict__ X, const ushort* __restrict__ wlt,
    const ushort* __restrict__ wcb, const float* __restrict__ bconv,
    const float* __restrict__ pos, float* __restrict__ out) {
  const int tid  = threadIdx.x;
  const int wave = tid >> 6;
  const int lane = tid & 63;
  const int lr   = lane & 15;
  const int lq   = lane >> 4;
  const int gw    = blockIdx.x * 4 + wave;     // 0..2047
  const int batch = gw >> 8;                   // 256 waves per batch
  const int n0    = (gw & 255) << 5;           // 32 rows per wave
  const int* Xb   = X + batch * SEQ;
  float* outb     = out + (size_t)batch * SEQ * DIM;

  if (n0 == 0 || n0 == SEQ - 32)
    conv_wave<true>(Xb, wlt, wcb, bconv, pos, outb, n0, lr, lq);
  else
    conv_wave<false>(Xb, wlt, wcb, bconv, pos, outb, n0, lr, lq);
}

// ---------------------------------------------------------------------------
extern "C" void kernel_launch(void* const* d_in, const int* in_sizes, int n_in,
                              void* d_out, int out_size, void* d_ws, size_t ws_size,
                              hipStream_t stream) {
  const int*   X     = (const int*)d_in[0];
  const float* wlin  = (const float*)d_in[1];
  const float* blin  = (const float*)d_in[2];
  const float* wconv = (const float*)d_in[3];
  const float* bconv = (const float*)d_in[4];
  const float* pos   = (const float*)d_in[5];
  float*       out   = (float*)d_out;

  ushort* wcb = (ushort*)d_ws;                       // 163,840 B
  ushort* wlt = (ushort*)((char*)d_ws + 262144);     // 25.6 MB

  hipLaunchKernelGGL(prep, dim3(WLT_BLOCKS + WCONV_BLOCKS), dim3(256), 0, stream,
                     wlin, blin, wconv, wlt, wcb);
  hipLaunchKernelGGL(conv_main, dim3(512), dim3(256), 0, stream,
                     X, wlt, wcb, bconv, pos, out);
}

// Round 5
// 160.457 us; speedup vs baseline: 1.0051x; 1.0051x over previous
//
#include <hip/hip_runtime.h>
#include <hip/hip_bf16.h>
#include <stdint.h>

#define VOCAB 100000
#define SEQ   8192
#define BATCH 8
#define DIM   128

#define WLT_BLOCKS 1563          // ceil(100000/64)
#define WCONV_BLOCKS 320         // 5*128*128 / 256

typedef short bf16x8 __attribute__((ext_vector_type(8)));
typedef float f32x4  __attribute__((ext_vector_type(4)));

__device__ __forceinline__ ushort f2bf(float f) {
  union { float f; uint32_t u; } v; v.f = f;
  uint32_t u = v.u;
  return (ushort)((u + 0x7FFF + ((u >> 16) & 1)) >> 16);  // RNE; inputs never NaN
}

// ---------------------------------------------------------------------------
// Prep kernel (merged): blocks [0, WLT_BLOCKS) build wlt via LDS tile
// transpose; blocks [WLT_BLOCKS, +320) repack W_conv (d,i,k)->wcb[k][d][i].
// ---------------------------------------------------------------------------
__global__ __launch_bounds__(256) void prep(
    const float* __restrict__ wlin, const float* __restrict__ blin,
    const float* __restrict__ wconv, ushort* __restrict__ wlt,
    ushort* __restrict__ wcb) {
  __shared__ float tile[128 * 65];
  const int tid = threadIdx.x;

  if (blockIdx.x >= WLT_BLOCKS) {
    int e = (blockIdx.x - WLT_BLOCKS) * 256 + tid;   // < 81920
    int k = e / (DIM * DIM);
    int rem = e % (DIM * DIM);
    int d = rem / DIM, i = rem % DIM;
    wcb[e] = f2bf(wconv[(d * DIM + i) * 5 + k]);
    return;
  }

  const int t0 = blockIdx.x * 64;

  // Phase A: float4 coalesced reads of W_lin rows into fp32 LDS tile.
  const int c4 = (tid & 15) * 4;
  const int rbase = tid >> 4;
  const bool cvalid = (t0 + c4) < VOCAB;   // VOCAB%4==0 -> whole float4 ok
#pragma unroll
  for (int p = 0; p < 8; ++p) {
    int r = p * 16 + rbase;
    float4 v = make_float4(0.f, 0.f, 0.f, 0.f);
    if (cvalid) v = *(const float4*)(wlin + (size_t)r * VOCAB + t0 + c4);
    float* dst = &tile[r * 65 + c4];
    dst[0] = v.x; dst[1] = v.y; dst[2] = v.z; dst[3] = v.w;
  }
  __syncthreads();

  // Phase B: transposed reads (+bias), bf16 pack, contiguous 1KB/wave stores.
  const int chunk = tid & 15;
  float bias8[8];
#pragma unroll
  for (int j = 0; j < 8; ++j) bias8[j] = blin[chunk * 8 + j];

#pragma unroll
  for (int p = 0; p < 4; ++p) {
    int tl = (tid >> 4) + p * 16;
    int t  = t0 + tl;
    if (t >= VOCAB) continue;
    ushort u[8];
#pragma unroll
    for (int j = 0; j < 8; ++j)
      u[j] = f2bf(tile[(chunk * 8 + j) * 65 + tl] + bias8[j]);
    *(uint4*)(wlt + (size_t)t * DIM + chunk * 8) = *(const uint4*)u;
  }
}

// ---------------------------------------------------------------------------
// Main: block = 128 rows x 32 cols (col-quarter q = blockIdx&3).
// B staged ONCE into LDS in FRAGMENT order: slot s=(k*4+kk)*2+nt holds the
// 64-lane fragment contiguously (lane*16B) -> ds_write/ds_read both
// lane-linear (2-way/free). 40 KB LDS -> 4 blocks/CU; 8192 waves total
// -> 16 waves/CU, 4/SIMD. One barrier total; compute phase is barrier-free:
// A-fragments gathered directly from wlt rows (verified R4), B from LDS.
// ---------------------------------------------------------------------------
template <bool EDGE>
__device__ __forceinline__ void conv_wave(
    const int* __restrict__ Xb, const ushort* __restrict__ wlt,
    const ushort* __restrict__ Blds, const float* __restrict__ bconv,
    const float* __restrict__ pos, float* __restrict__ outb,
    int n0, int q, int lane, int lr, int lq) {
  int  tok[2][5];
  bool vld[2][5];
#pragma unroll
  for (int mt = 0; mt < 2; ++mt)
#pragma unroll
    for (int k = 0; k < 5; ++k) {
      int n = n0 + mt * 16 + lr + k - 2;
      bool v = EDGE ? (n >= 0 && n < SEQ) : true;
      vld[mt][k] = v;
      tok[mt][k] = v ? Xb[n] : 0;
    }

  f32x4 acc[2][2];
#pragma unroll
  for (int a = 0; a < 2; ++a)
#pragma unroll
    for (int b = 0; b < 2; ++b) acc[a][b] = (f32x4)0.f;

  const int colA = lq * 8;
#pragma unroll
  for (int k = 0; k < 5; ++k) {
    bf16x8 A[2][4];
#pragma unroll
    for (int mt = 0; mt < 2; ++mt)
#pragma unroll
      for (int kk = 0; kk < 4; ++kk) {
        bf16x8 v = *(const bf16x8*)(wlt + ((size_t)tok[mt][k] << 7) + kk * 32 + colA);
        A[mt][kk] = (EDGE && !vld[mt][k]) ? (bf16x8)(short)0 : v;
      }
#pragma unroll
    for (int kk = 0; kk < 4; ++kk) {
      bf16x8 B[2];
#pragma unroll
      for (int nt = 0; nt < 2; ++nt)
        B[nt] = *(const bf16x8*)(Blds + (((k * 4 + kk) * 2 + nt) << 9) + lane * 8);
#pragma unroll
      for (int mt = 0; mt < 2; ++mt)
#pragma unroll
        for (int nt = 0; nt < 2; ++nt)
          acc[mt][nt] = __builtin_amdgcn_mfma_f32_16x16x32_bf16(
              A[mt][kk], B[nt], acc[mt][nt], 0, 0, 0);
    }
  }

  // epilogue: + b_conv[d] + pos[n][d]; C layout: col=lr, row=lq*4+rr
  float bc[2];
#pragma unroll
  for (int nt = 0; nt < 2; ++nt) bc[nt] = bconv[q * 32 + nt * 16 + lr];
#pragma unroll
  for (int mt = 0; mt < 2; ++mt) {
#pragma unroll
    for (int rr = 0; rr < 4; ++rr) {
      int gn = n0 + mt * 16 + lq * 4 + rr;
      const float* posrow = pos + (size_t)gn * DIM;
      float* orow = outb + (size_t)gn * DIM;
#pragma unroll
      for (int nt = 0; nt < 2; ++nt) {
        int d = q * 32 + nt * 16 + lr;
        orow[d] = acc[mt][nt][rr] + bc[nt] + posrow[d];
      }
    }
  }
}

__global__ __launch_bounds__(256, 4) void conv_main(
    const int* __restrict__ X, const ushort* __restrict__ wlt,
    const ushort* __restrict__ wcb, const float* __restrict__ bconv,
    const float* __restrict__ pos, float* __restrict__ out) {
  __shared__ __align__(16) ushort Blds[20480];   // 40 slots x 512 ushorts

  const int tid = threadIdx.x;
  const int q   = blockIdx.x & 3;                // col quarter
  const int gb  = blockIdx.x >> 2;               // 0..511 row-tile
  const int batch = gb >> 6;
  const int nbb   = (gb & 63) << 7;              // within-seq base (128 rows)

  // ---- stage B: 2560 fragment-slots of 16B; read wcb, write lane-linear ----
#pragma unroll
  for (int it = 0; it < 10; ++it) {
    int s  = it * 256 + tid;                     // slot*64 + lane
    int f  = s >> 6, l = s & 63;
    int k  = f >> 3, kk = (f >> 1) & 3, nt = f & 1;
    int flr = l & 15, flq = l >> 4;
    int d  = q * 32 + nt * 16 + flr;
    uint4 v = *(const uint4*)(wcb + ((size_t)(k * DIM + d) * DIM + kk * 32 + flq * 8));
    *(uint4*)&Blds[s * 8] = v;
  }
  __syncthreads();

  const int wave = tid >> 6;
  const int lane = tid & 63;
  const int lr   = lane & 15;
  const int lq   = lane >> 4;
  const int n0   = nbb + wave * 32;
  const int* Xb  = X + batch * SEQ;
  float* outb    = out + (size_t)batch * SEQ * DIM;

  if (n0 == 0 || n0 == SEQ - 32)
    conv_wave<true>(Xb, wlt, Blds, bconv, pos, outb, n0, q, lane, lr, lq);
  else
    conv_wave<false>(Xb, wlt, Blds, bconv, pos, outb, n0, q, lane, lr, lq);
}

// ---------------------------------------------------------------------------
extern "C" void kernel_launch(void* const* d_in, const int* in_sizes, int n_in,
                              void* d_out, int out_size, void* d_ws, size_t ws_size,
                              hipStream_t stream) {
  const int*   X     = (const int*)d_in[0];
  const float* wlin  = (const float*)d_in[1];
  const float* blin  = (const float*)d_in[2];
  const float* wconv = (const float*)d_in[3];
  const float* bconv = (const float*)d_in[4];
  const float* pos   = (const float*)d_in[5];
  float*       out   = (float*)d_out;

  ushort* wcb = (ushort*)d_ws;                       // 163,840 B
  ushort* wlt = (ushort*)((char*)d_ws + 262144);     // 25.6 MB

  hipLaunchKernelGGL(prep, dim3(WLT_BLOCKS + WCONV_BLOCKS), dim3(256), 0, stream,
                     wlin, blin, wconv, wlt, wcb);
  hipLaunchKernelGGL(conv_main, dim3(2048), dim3(256), 0, stream,
                     X, wlt, wcb, bconv, pos, out);
}